// Round 1
// baseline (624.134 us; speedup 1.0000x reference)
//
#include <hip/hip_runtime.h>
#include <stdint.h>

// K-Planes hash-grid encoder, MI355X.
// thread = (point, level); lvl = tid&15 so a 16-thread group covers all levels
// of one point -> 128B contiguous float2 output stores, broadcast point loads.

#define NPTS 524288u
#define TMASK 0x7FFFFu      // TABLE_SIZE = 2^19
#define PRIME1 2654435761u

// floor(16 * 1.3819^l) computed in float64 (matches numpy reference exactly)
__constant__ float c_res[16] = {
    16.f, 22.f, 30.f, 42.f, 58.f, 80.f, 111.f, 153.f,
    212.f, 294.f, 406.f, 561.f, 775.f, 1072.f, 1481.f, 2047.f
};

extern "C" __global__ __launch_bounds__(256) void kplane_fwd(
    const float* __restrict__ pts,
    const float2* __restrict__ tab,   // (3, 16, 2^19) float2
    float2* __restrict__ out)         // (NPTS, 16) float2
{
    const uint32_t tid = blockIdx.x * 256u + threadIdx.x;
    const uint32_t pt  = tid >> 4;
    const uint32_t lvl = tid & 15u;

    const float x = pts[pt * 3u + 0u];
    const float y = pts[pt * 3u + 1u];
    const float z = pts[pt * 3u + 2u];
    const float res = c_res[lvl];

    // plane combos: (0,1)=(x,y), (0,2)=(x,z), (1,2)=(y,z)
    const float a0[3] = {x, x, y};
    const float a1[3] = {y, z, z};

    float p0 = 1.f, p1 = 1.f;

#pragma unroll
    for (int pl = 0; pl < 3; ++pl) {
        const float s0 = a0[pl] * res;
        const float s1 = a1[pl] * res;
        const float f0 = floorf(s0);
        const float f1 = floorf(s1);
        const float r0 = s0 - f0;     // frac, exact f32 match to reference
        const float r1 = s1 - f1;
        const uint32_t u0 = (uint32_t)f0;
        const uint32_t u1 = (uint32_t)f1;

        // h = c0*1 ^ c1*PRIME1 (uint32 wrap), idx = h & (2^19-1)
        const uint32_t hy0 = u1 * PRIME1;
        const uint32_t hy1 = hy0 + PRIME1;          // (u1+1)*PRIME1
        const uint32_t base = ((uint32_t)pl * 16u + lvl) * 524288u;

        const float2 t00 = tab[base + (( u0        ^ hy0) & TMASK)];
        const float2 t01 = tab[base + (( u0        ^ hy1) & TMASK)];
        const float2 t10 = tab[base + (((u0 + 1u)  ^ hy0) & TMASK)];
        const float2 t11 = tab[base + (((u0 + 1u)  ^ hy1) & TMASK)];

        const float w00 = (1.f - r0) * (1.f - r1);
        const float w01 = (1.f - r0) * r1;
        const float w10 = r0 * (1.f - r1);
        const float w11 = r0 * r1;

        const float e0 = w00 * t00.x + w01 * t01.x + w10 * t10.x + w11 * t11.x;
        const float e1 = w00 * t00.y + w01 * t01.y + w10 * t10.y + w11 * t11.y;

        p0 *= e0;
        p1 *= e1;
    }

    out[pt * 16u + lvl] = make_float2(p0, p1);
}

extern "C" void kernel_launch(void* const* d_in, const int* in_sizes, int n_in,
                              void* d_out, int out_size, void* d_ws, size_t ws_size,
                              hipStream_t stream) {
    const float*  pts = (const float*)d_in[0];
    const float2* tab = (const float2*)d_in[1];
    float2*       out = (float2*)d_out;

    const uint32_t n_threads = NPTS * 16u;        // 8.4M threads
    dim3 grid(n_threads / 256u), block(256u);
    hipLaunchKernelGGL(kplane_fwd, grid, block, 0, stream, pts, tab, out);
}

// Round 2
// 353.117 us; speedup vs baseline: 1.7675x; 1.7675x over previous
//
#include <hip/hip_runtime.h>
#include <stdint.h>

// K-Planes hash-grid encoder, MI355X.
// Strategy: 3 plane passes + transpose. Each pass partitions levels across
// XCDs (block b -> XCD b&7, hardware round-robin dispatch model) so each
// XCD's 4 MB L2 holds exactly one (plane,level) hash table at a time.
// Per-pass partial products accumulate in level-major ws (coalesced RMW);
// final kernel transposes to the pt-major output layout.

#define NPTS   524288u
#define TSIZE  524288u      // 2^19 entries per (plane,level) table
#define TMASK  0x7FFFFu
#define PRIME1 2654435761u

// floor(16 * 1.3819^l) computed in float64 (matches numpy reference exactly)
__constant__ float c_res[16] = {
    16.f, 22.f, 30.f, 42.f, 58.f, 80.f, 111.f, 153.f,
    212.f, 294.f, 406.f, 561.f, 775.f, 1072.f, 1481.f, 2047.f
};

// ---------- per-plane gather pass, level-grouped for XCD-L2 residency -------
template <int P, bool FIRST>
__global__ __launch_bounds__(256) void kplane_pass(
    const float* __restrict__ pts,
    const float2* __restrict__ tab,   // (3, 16, 2^19) float2
    float2* __restrict__ ws)          // (16, NPTS) float2, level-major
{
    const uint32_t b     = blockIdx.x;
    const uint32_t xcd   = b & 7u;
    const uint32_t s     = b >> 3;
    const uint32_t gi    = s >> 11;          // 0..1 : sequential per-XCD phase
    const uint32_t chunk = s & 2047u;        // 2048 chunks x 256 pts = NPTS
    const uint32_t lvl   = gi * 8u + xcd;    // XCD x: level x, then x+8
    const uint32_t pt    = chunk * 256u + threadIdx.x;

    // plane combos: P=0 -> (x,y), P=1 -> (x,z), P=2 -> (y,z)
    constexpr int c0 = (P == 2) ? 1 : 0;
    constexpr int c1 = (P == 0) ? 1 : 2;

    const float a0  = pts[pt * 3u + c0];
    const float a1  = pts[pt * 3u + c1];
    const float res = c_res[lvl];

    const float s0 = a0 * res;
    const float s1 = a1 * res;
    const float f0 = floorf(s0);
    const float f1 = floorf(s1);
    const float r0 = s0 - f0;                // exact f32 match to reference
    const float r1 = s1 - f1;
    const uint32_t u0 = (uint32_t)f0;
    const uint32_t u1 = (uint32_t)f1;

    // h = c0*1 ^ c1*PRIME1 (uint32 wrap), idx = h & (2^19-1)
    const uint32_t hy0  = u1 * PRIME1;
    const uint32_t hy1  = hy0 + PRIME1;      // (u1+1)*PRIME1
    const uint32_t base = ((uint32_t)P * 16u + lvl) * TSIZE;

    const float2 t00 = tab[base + (( u0       ^ hy0) & TMASK)];
    const float2 t01 = tab[base + (( u0       ^ hy1) & TMASK)];
    const float2 t10 = tab[base + (((u0 + 1u) ^ hy0) & TMASK)];
    const float2 t11 = tab[base + (((u0 + 1u) ^ hy1) & TMASK)];

    const float w00 = (1.f - r0) * (1.f - r1);
    const float w01 = (1.f - r0) * r1;
    const float w10 = r0 * (1.f - r1);
    const float w11 = r0 * r1;

    const float e0 = w00 * t00.x + w01 * t01.x + w10 * t10.x + w11 * t11.x;
    const float e1 = w00 * t00.y + w01 * t01.y + w10 * t10.y + w11 * t11.y;

    const uint32_t widx = lvl * NPTS + pt;   // coalesced 2 KB per block
    if (FIRST) {
        ws[widx] = make_float2(e0, e1);
    } else {
        const float2 prev = ws[widx];
        ws[widx] = make_float2(prev.x * e0, prev.y * e1);
    }
}

// ---------- ws (level-major) -> out (pt-major) ------------------------------
__global__ __launch_bounds__(256) void kplane_transpose(
    const float2* __restrict__ ws, float2* __restrict__ out)
{
    const uint32_t tid = blockIdx.x * 256u + threadIdx.x;
    const uint32_t lvl = tid & 15u;
    const uint32_t pt  = tid >> 4;
    out[tid] = ws[lvl * NPTS + pt];          // out[pt*16+lvl] == out[tid]
}

// ---------- fallback: round-1 monolithic kernel (if ws too small) -----------
__global__ __launch_bounds__(256) void kplane_mono(
    const float* __restrict__ pts,
    const float2* __restrict__ tab,
    float2* __restrict__ out)
{
    const uint32_t tid = blockIdx.x * 256u + threadIdx.x;
    const uint32_t pt  = tid >> 4;
    const uint32_t lvl = tid & 15u;

    const float x = pts[pt * 3u + 0u];
    const float y = pts[pt * 3u + 1u];
    const float z = pts[pt * 3u + 2u];
    const float res = c_res[lvl];

    const float a0[3] = {x, x, y};
    const float a1[3] = {y, z, z};
    float p0 = 1.f, p1 = 1.f;

#pragma unroll
    for (int pl = 0; pl < 3; ++pl) {
        const float s0 = a0[pl] * res;
        const float s1 = a1[pl] * res;
        const float f0 = floorf(s0);
        const float f1 = floorf(s1);
        const float r0 = s0 - f0;
        const float r1 = s1 - f1;
        const uint32_t u0 = (uint32_t)f0;
        const uint32_t u1 = (uint32_t)f1;
        const uint32_t hy0 = u1 * PRIME1;
        const uint32_t hy1 = hy0 + PRIME1;
        const uint32_t base = ((uint32_t)pl * 16u + lvl) * TSIZE;

        const float2 t00 = tab[base + (( u0       ^ hy0) & TMASK)];
        const float2 t01 = tab[base + (( u0       ^ hy1) & TMASK)];
        const float2 t10 = tab[base + (((u0 + 1u) ^ hy0) & TMASK)];
        const float2 t11 = tab[base + (((u0 + 1u) ^ hy1) & TMASK)];

        const float w00 = (1.f - r0) * (1.f - r1);
        const float w01 = (1.f - r0) * r1;
        const float w10 = r0 * (1.f - r1);
        const float w11 = r0 * r1;

        p0 *= w00 * t00.x + w01 * t01.x + w10 * t10.x + w11 * t11.x;
        p1 *= w00 * t00.y + w01 * t01.y + w10 * t10.y + w11 * t11.y;
    }
    out[pt * 16u + lvl] = make_float2(p0, p1);
}

extern "C" void kernel_launch(void* const* d_in, const int* in_sizes, int n_in,
                              void* d_out, int out_size, void* d_ws, size_t ws_size,
                              hipStream_t stream) {
    const float*  pts = (const float*)d_in[0];
    const float2* tab = (const float2*)d_in[1];
    float2*       out = (float2*)d_out;

    const size_t ws_needed = (size_t)16 * NPTS * sizeof(float2);  // 67 MB
    if (ws_size >= ws_needed) {
        float2* ws = (float2*)d_ws;
        dim3 grid(16u * (NPTS / 256u)), block(256u);   // 32768 blocks
        hipLaunchKernelGGL((kplane_pass<0, true >), grid, block, 0, stream, pts, tab, ws);
        hipLaunchKernelGGL((kplane_pass<1, false>), grid, block, 0, stream, pts, tab, ws);
        hipLaunchKernelGGL((kplane_pass<2, false>), grid, block, 0, stream, pts, tab, ws);
        dim3 tgrid((NPTS * 16u) / 256u);               // 32768 blocks
        hipLaunchKernelGGL(kplane_transpose, tgrid, block, 0, stream, ws, out);
    } else {
        dim3 grid((NPTS * 16u) / 256u), block(256u);
        hipLaunchKernelGGL(kplane_mono, grid, block, 0, stream, pts, tab, out);
    }
}